// Round 21
// baseline (146.187 us; speedup 1.0000x reference)
//
#include <hip/hip_runtime.h>
#include <hip/hip_bf16.h>

// ---------------------------------------------------------------------------
// Fused MHA forward: x@Wq/Wk/Wv -> heads -> softmax(QK^T/sqrt(dk))V -> @Wo
// B=2, S=2048, D=1024, H=16, Dk=64.  All matmuls via bf16 MFMA, fp32 accum.
// r19: gemm_qkv gains attn-style double-buffered staging (one barrier per
// K-step, loads overlap compute).  gemm_out kept single-buffered as control.
// ---------------------------------------------------------------------------

#define SEQ 2048
#define DMODEL 1024
#define NHEAD 16
#define DK 64
#define NBATCH 2
#define NBH 32
#define MTOT 4096

typedef __attribute__((ext_vector_type(4)))  float  f32x4;
typedef __attribute__((ext_vector_type(16))) float  f32x16;
typedef __attribute__((ext_vector_type(8)))  short  bf16x8;
typedef __attribute__((ext_vector_type(4)))  short  bf16x4;
typedef __attribute__((ext_vector_type(4)))  unsigned short u16x4;
typedef __attribute__((ext_vector_type(2)))  unsigned int u32x2;

// scale folded into Q: (1/sqrt(64)) * log2(e) so softmax can use exp2
#define QSCALE 0.18033688f

// bf16 convert via scalar cast -> compiler emits v_cvt_pk_bf16_f32 (m240)
__device__ __forceinline__ unsigned short f2bf(float x) {
  union { __hip_bfloat16 h; unsigned short u; } cv;
  cv.h = __float2bfloat16(x);
  return cv.u;
}

// packed f32 pair -> bf16 pair (lo = first arg)
__device__ __forceinline__ unsigned cvtpk(float lo, float hi) {
  unsigned r;
  asm("v_cvt_pk_bf16_f32 %0, %1, %2" : "=v"(r) : "v"(lo), "v"(hi));
  return r;
}

#define EXP2(x) __builtin_amdgcn_exp2f(x)

__device__ __forceinline__ float fmax3(float a, float b, float c) {
  return fmaxf(fmaxf(a, b), c);  // clang fuses to v_max3_f32
}

__device__ __forceinline__ void gload16(const void* g, void* l) {
  __builtin_amdgcn_global_load_lds(
      (const __attribute__((address_space(1))) unsigned int*)g,
      (__attribute__((address_space(3))) unsigned int*)l, 16, 0, 0);
}

// ---------------------------------------------------------------------------
// conv_all: blocks [0,1024) transpose W0..W3 (fp32->bf16, W[k][n]->Wt[n][k]);
//           blocks [1024,2048) convert x fp32->bf16 (16 elems/thread).
// ---------------------------------------------------------------------------
__global__ __launch_bounds__(256) void conv_all(
    const float* __restrict__ X, unsigned short* __restrict__ Xb,
    const float* __restrict__ W0, const float* __restrict__ W1,
    const float* __restrict__ W2, const float* __restrict__ W3,
    unsigned short* __restrict__ T0, unsigned short* __restrict__ T1,
    unsigned short* __restrict__ T2, unsigned short* __restrict__ T3) {
  __shared__ float tile[64][65];
  const int b = blockIdx.x;
  if (b >= 1024) {
    size_t i = ((size_t)(b - 1024) * 256 + threadIdx.x) * 16;
#pragma unroll
    for (int c = 0; c < 4; ++c) {
      f32x4 v = *(const f32x4*)&X[i + c * 4];
      u16x4 pk;
      pk[0] = f2bf(v[0]); pk[1] = f2bf(v[1]);
      pk[2] = f2bf(v[2]); pk[3] = f2bf(v[3]);
      *(u16x4*)&Xb[i + c * 4] = pk;
    }
    return;
  }
  const int z = b >> 8, rem = b & 255;
  const float* W; unsigned short* T;
  switch (z) {
    case 0: W = W0; T = T0; break;
    case 1: W = W1; T = T1; break;
    case 2: W = W2; T = T2; break;
    default: W = W3; T = T3; break;
  }
  const int k0 = (rem & 15) * 64, n0 = (rem >> 4) * 64;
  const int tr = threadIdx.x >> 4, tc = (threadIdx.x & 15) * 4;
#pragma unroll
  for (int i = 0; i < 4; ++i) {
    int r = tr + i * 16;
    f32x4 v = *(const f32x4*)&W[(size_t)(k0 + r) * DMODEL + n0 + tc];
    tile[r][tc + 0] = v[0]; tile[r][tc + 1] = v[1];
    tile[r][tc + 2] = v[2]; tile[r][tc + 3] = v[3];
  }
  __syncthreads();
#pragma unroll
  for (int i = 0; i < 4; ++i) {
    int nr = tr + i * 16;
    u16x4 pk;
    pk[0] = f2bf(tile[tc + 0][nr]); pk[1] = f2bf(tile[tc + 1][nr]);
    pk[2] = f2bf(tile[tc + 2][nr]); pk[3] = f2bf(tile[tc + 3][nr]);
    *(u16x4*)&T[(size_t)(n0 + nr) * DMODEL + k0 + tc] = pk;
  }
}

// ---------------------------------------------------------------------------
// gemm_qkv: fused GEMM over N=3072 (Q|K|V), grid 768, XCD n-chunking,
// which-branch hoisted around duplicated branch-free K-loops.
// Double-buffered staging — sync; STAGE(kt+1, other buf); compute(kt).
// One barrier per K-step; loads land under a full compute phase instead of
// a serial in-step vmcnt(0) drain (r18 PMC: MfmaUtil 16%, VALUBusy 16% ->
// ~80% stall on the single-buffered drain).  LDS 64KB -> 2 blocks/CU.
//   Q/K arm: SWAPPED MFMA operands -> acc regs index d -> 8B d-contig stores.
//   V arm:   normal order -> 8B s-contig stores into Vt.
// ---------------------------------------------------------------------------
__global__ __launch_bounds__(256) void gemm_qkv(
    const short* __restrict__ A, const short* __restrict__ Bt,
    const float* __restrict__ bq, const float* __restrict__ bk,
    const float* __restrict__ bv, unsigned short* __restrict__ Qg,
    unsigned short* __restrict__ Kg, unsigned short* __restrict__ Vtg) {
  const int tid = threadIdx.x;
  const int lane = tid & 63, w = tid >> 6;
  const int lq = lane & 15, g = lane >> 4;
  const int bidg = blockIdx.x;
  const int j = bidg >> 3;
  const int n_t = (bidg & 7) * 3 + (j % 3);
  const int m0 = (j / 3) * 128, n0 = n_t * 128;
  const int wm = (w >> 1) * 64, wn = (w & 1) * 64;
  const int which = n0 >> 10;

  __shared__ __attribute__((aligned(16))) short abuf[2][128 * 64];
  __shared__ __attribute__((aligned(16))) short bbuf[2][128 * 64];

  f32x4 acc[4][4] = {};
  const char* Ab = (const char*)A;
  const char* Bb = (const char*)Bt;

#define QKV_STAGE(KT, BI)                                                  \
  do {                                                                     \
    _Pragma("unroll")                                                      \
    for (int i = 0; i < 4; ++i) {                                          \
      int y = tid * 16 + i * 4096;                                         \
      int row = y >> 7, cb = y & 127;                                      \
      gload16(Ab + (size_t)(m0 + row) * 2048 + (KT) * 128 + cb,            \
              (char*)abuf[BI] + y);                                        \
      gload16(Bb + (size_t)(n0 + row) * 2048 + (KT) * 128 + cb,            \
              (char*)bbuf[BI] + y);                                        \
    }                                                                      \
  } while (0)

  if (which == 2) {
    // ---------------- V arm: normal operand order ----------------
    QKV_STAGE(0, 0);
    for (int kt = 0; kt < 16; ++kt) {
      const int bi = kt & 1;
      __syncthreads();
      if (kt < 15) QKV_STAGE(kt + 1, bi ^ 1);
#pragma unroll
      for (int ks = 0; ks < 2; ++ks) {
        bf16x8 af[4], bfr[4];
#pragma unroll
        for (int i = 0; i < 4; ++i) {
          af[i]  = *(const bf16x8*)&abuf[bi][(wm + i * 16 + lq) * 64 + ks * 32 + g * 8];
          bfr[i] = *(const bf16x8*)&bbuf[bi][(wn + i * 16 + lq) * 64 + ks * 32 + g * 8];
        }
#pragma unroll
        for (int mi = 0; mi < 4; ++mi)
#pragma unroll
          for (int ni = 0; ni < 4; ++ni)
            acc[mi][ni] = __builtin_amdgcn_mfma_f32_16x16x32_bf16(
                af[mi], bfr[ni], acc[mi][ni], 0, 0, 0);
      }
    }
    // V epilogue: rows(reg)=m(s), col(lane)=n(d) -> Vt[bh][d][s], 8B stores
#pragma unroll
    for (int mi = 0; mi < 4; ++mi) {
#pragma unroll
      for (int ni = 0; ni < 4; ++ni) {
        const int nl = (n0 & 1023) + wn + ni * 16 + lq;
        const int mbase = m0 + wm + mi * 16 + g * 4;
        const float bs = bv[nl];
        const int h = nl >> 6, d = nl & 63;
        const int b = mbase >> 11, s = mbase & 2047;
        u16x4 pk;
#pragma unroll
        for (int r = 0; r < 4; ++r) pk[r] = f2bf(acc[mi][ni][r] + bs);
        *(u16x4*)&Vtg[(size_t)((b * NHEAD + h) * DK + d) * SEQ + s] = pk;
      }
    }
  } else {
    // ---------------- Q/K arm: swapped operand order ----------------
    QKV_STAGE(0, 0);
    for (int kt = 0; kt < 16; ++kt) {
      const int bi = kt & 1;
      __syncthreads();
      if (kt < 15) QKV_STAGE(kt + 1, bi ^ 1);
#pragma unroll
      for (int ks = 0; ks < 2; ++ks) {
        bf16x8 af[4], bfr[4];
#pragma unroll
        for (int i = 0; i < 4; ++i) {
          af[i]  = *(const bf16x8*)&abuf[bi][(wm + i * 16 + lq) * 64 + ks * 32 + g * 8];
          bfr[i] = *(const bf16x8*)&bbuf[bi][(wn + i * 16 + lq) * 64 + ks * 32 + g * 8];
        }
#pragma unroll
        for (int mi = 0; mi < 4; ++mi)
#pragma unroll
          for (int ni = 0; ni < 4; ++ni)
            acc[mi][ni] = __builtin_amdgcn_mfma_f32_16x16x32_bf16(
                bfr[ni], af[mi], acc[mi][ni], 0, 0, 0);
      }
    }
    // Q/K epilogue: rows(reg)=n(d), col(lane)=m(s) -> [bh][s][d], 8B stores
    const float* bias = (which == 0) ? bq : bk;
    unsigned short* o = (which == 0) ? Qg : Kg;
    const float sc = (which == 0) ? QSCALE : 1.0f;
#pragma unroll
    for (int mi = 0; mi < 4; ++mi) {
#pragma unroll
      for (int ni = 0; ni < 4; ++ni) {
        const int nlb = (n0 & 1023) + wn + ni * 16 + g * 4;
        const int m = m0 + wm + mi * 16 + lq;
        const int b = m >> 11, s = m & 2047;
        const int h = nlb >> 6, d = nlb & 63;
        const f32x4 bsv = *(const f32x4*)&bias[nlb];
        u16x4 pk;
#pragma unroll
        for (int r = 0; r < 4; ++r)
          pk[r] = f2bf((acc[mi][ni][r] + bsv[r]) * sc);
        *(u16x4*)&o[(size_t)((b * NHEAD + h) * SEQ + s) * DK + d] = pk;
      }
    }
  }
#undef QKV_STAGE
}

// ---------------------------------------------------------------------------
// gemm_out: final projection, fp32 out.  Linear grid 256; xcd = bid&7 owns
// n-tile bid&7.  Kept single-buffered (in-run control vs gemm_qkv's dbuf).
// ---------------------------------------------------------------------------
__global__ __launch_bounds__(256) void gemm_out(const short* __restrict__ A,
                                                const short* __restrict__ Bt,
                                                const float* __restrict__ bias,
                                                float* __restrict__ o) {
  const int tid = threadIdx.x;
  const int lane = tid & 63, w = tid >> 6;
  const int lq = lane & 15, g = lane >> 4;
  const int m0 = (blockIdx.x >> 3) * 128, n0 = (blockIdx.x & 7) * 128;
  const int wm = (w >> 1) * 64, wn = (w & 1) * 64;

  __shared__ __attribute__((aligned(16))) short abuf[128 * 64];
  __shared__ __attribute__((aligned(16))) short bbuf[128 * 64];

  f32x4 acc[4][4] = {};
  const char* Ab = (const char*)A;
  const char* Bb = (const char*)Bt;

  for (int kt = 0; kt < 16; ++kt) {
    __syncthreads();
#pragma unroll
    for (int i = 0; i < 4; ++i) {
      int y = tid * 16 + i * 4096;
      int row = y >> 7, cb = y & 127;
      gload16(Ab + (size_t)(m0 + row) * 2048 + kt * 128 + cb, (char*)abuf + y);
      gload16(Bb + (size_t)(n0 + row) * 2048 + kt * 128 + cb, (char*)bbuf + y);
    }
    __syncthreads();
#pragma unroll
    for (int ks = 0; ks < 2; ++ks) {
      bf16x8 af[4], bfr[4];
#pragma unroll
      for (int i = 0; i < 4; ++i) {
        af[i]  = *(const bf16x8*)&abuf[(wm + i * 16 + lq) * 64 + ks * 32 + g * 8];
        bfr[i] = *(const bf16x8*)&bbuf[(wn + i * 16 + lq) * 64 + ks * 32 + g * 8];
      }
#pragma unroll
      for (int mi = 0; mi < 4; ++mi)
#pragma unroll
        for (int ni = 0; ni < 4; ++ni)
          acc[mi][ni] = __builtin_amdgcn_mfma_f32_16x16x32_bf16(
              af[mi], bfr[ni], acc[mi][ni], 0, 0, 0);
    }
  }

#pragma unroll
  for (int mi = 0; mi < 4; ++mi) {
#pragma unroll
    for (int ni = 0; ni < 4; ++ni) {
      const int n = n0 + wn + ni * 16 + lq;
      const int mbase = m0 + wm + mi * 16 + g * 4;
      const float bs = bias[n];
#pragma unroll
      for (int r = 0; r < 4; ++r)
        o[(size_t)(mbase + r) * DMODEL + n] = acc[mi][ni][r] + bs;
    }
  }
}

// ---------------------------------------------------------------------------
// attn: flash attention, 32x32x16 MFMA, swapped QK^T, in-register P (T12).
// 2-deep double-buffer staging with __syncthreads; KBLK=64, QBLK=128
// (4 waves x 32 q), grid 512, XCD-chunk swizzle.  Measured 58.8us —
// the local optimum of this structure (r12/r14/r16 ablation bracket).
// ---------------------------------------------------------------------------
__global__ __launch_bounds__(256) void attn_kernel(
    const short* __restrict__ Qg, const short* __restrict__ Kg,
    const short* __restrict__ Vtg, unsigned short* __restrict__ Og) {
  const int tid = threadIdx.x, lane = tid & 63, w = tid >> 6;
  const int l5 = lane & 31, hi = lane >> 5;
  const int sw7 = l5 & 7, hi8 = hi * 8;
  // bijective XCD-chunk swizzle (512 % 8 == 0)
  const int bid = blockIdx.x;
  const int swz = (bid & 7) * 64 + (bid >> 3);
  const int bh = swz >> 4, q0 = (swz & 15) * 128;

  __shared__ __attribute__((aligned(16))) short kbuf[2][64 * 64];
  __shared__ __attribute__((aligned(16))) short vbuf[2][64 * 64];

  // Q fragments: B-operand, col q = l5, k(d) = ds*16 + hi*8 + j
  const short* qrow = Qg + ((size_t)bh * SEQ + q0 + w * 32 + l5) * DK;
  bf16x8 qf[4];
#pragma unroll
  for (int ds = 0; ds < 4; ++ds)
    qf[ds] = *(const bf16x8*)&qrow[ds * 16 + hi8];

  bf16x8 ones;
#pragma unroll
  for (int jj = 0; jj < 8; ++jj) ones[jj] = (short)0x3F80;  // bf16 1.0

  f32x16 oacc0 = {}, oacc1 = {};
  float m_run = -3.0e38f, l_run = 0.f;

  const char* kbase = (const char*)(Kg + (size_t)bh * SEQ * DK);
  const char* vbase = (const char*)(Vtg + (size_t)bh * DK * SEQ);

  // staging: linear LDS dest, pre-swizzled global source
  const int y0 = tid * 16, y1 = y0 + 4096;
  const int r0 = y0 >> 7, r1 = y1 >> 7;
  const int c0 = (y0 ^ (r0 << 4)) & 0x70;
  const int c1 = (y1 ^ (r1 << 4)) & 0x70;
  const int ksrc0 = (y0 & ~0x70) | c0;
  const int ksrc1 = (y1 & ~0x70) | c1;
  const int vsrc0 = r0 * 4096 + c0;
  const int vsrc1 = r1 * 4096 + c1;

#define STAGE(T, BI)                                                      \
  do {                                                                    \
    gload16(kbase + (size_t)(T) * 8192 + ksrc0, (char*)kbuf[BI] + y0);    \
    gload16(kbase + (size_t)(T) * 8192 + ksrc1, (char*)kbuf[BI] + y1);    \
    gload16(vbase + vsrc0 + (size_t)(T) * 128, (char*)vbuf[BI] + y0);     \
    gload16(vbase + vsrc1 + (size_t)(T) * 128, (char*)vbuf[BI] + y1);     \
  } while (0)

  STAGE(0, 0);

  for (int t = 0; t < 32; ++t) {
    const int bi = t & 1;
    __syncthreads();
    if (t < 31) STAGE(t + 1, bi ^ 1);

    const char* kb = (const char*)kbuf[bi];
    const char* vb = (const char*)vbuf[bi];

    // ---- S^T = K . Q^T : two 32-k subtiles, d = 64 in 4 steps of 16
    f32x16 s0 = {}, s1 = {};
    __builtin_amdgcn_s_setprio(1);
#pragma unroll
    for (int ds = 0; ds < 4; ++ds) {
      const int ch = ((ds * 2 + hi) ^ sw7) << 4;
      bf16x8 kf0 = *(const bf16x8*)(kb + l5 * 128 + ch);
      bf16x8 kf1 = *(const bf16x8*)(kb + (32 + l5) * 128 + ch);
      s0 = __builtin_amdgcn_mfma_f32_32x32x16_bf16(kf0, qf[ds], s0, 0, 0, 0);
      s1 = __builtin_amdgcn_mfma_f32_32x32x16_bf16(kf1, qf[ds], s1, 0, 0, 0);
    }
    __builtin_amdgcn_s_setprio(0);

    // ---- lane-local max over all 32 scores of this q (v_max3 tree)
    float t0 = fmax3(s0[0], s0[1], s0[2]);
    float t1 = fmax3(s0[3], s0[4], s0[5]);
    float t2 = fmax3(s0[6], s0[7], s0[8]);
    float t3 = fmax3(s0[9], s0[10], s0[11]);
    float t4 = fmax3(s0[12], s0[13], s0[14]);
    float t5 = fmax3(s1[0], s1[1], s1[2]);
    float t6 = fmax3(s1[3], s1[4], s1[5]);
    float t7 = fmax3(s1[6], s1[7], s1[8]);
    float t8 = fmax3(s1[9], s1[10], s1[11]);
    float t9 = fmax3(s1[12], s1[13], s1[14]);
    float u0 = fmax3(t0, t1, t2);
    float u1 = fmax3(t3, t4, s0[15]);
    float u2 = fmax3(t5, t6, t7);
    float u3 = fmax3(t8, t9, s1[15]);
    float lm = fmaxf(fmax3(u0, u1, u2), u3);

    // defer-max (THR=8, log2 domain): cross-lane + rescale only on slow path
    if (!__all(lm <= m_run + 8.0f)) {
      float vm = fmaxf(lm, __shfl_xor(lm, 32));  // partner lane: same q
      const float mn = fmaxf(m_run, vm);
      const float cr = EXP2(m_run - mn);
#pragma unroll
      for (int r = 0; r < 16; ++r) { oacc0[r] *= cr; oacc1[r] *= cr; }
      l_run *= cr;
      m_run = mn;
    }

#pragma unroll
    for (int r = 0; r < 16; ++r) {
      s0[r] = EXP2(s0[r] - m_run);
      s1[r] = EXP2(s1[r] - m_run);
    }

    // ---- PV: O^T[d][q] += V^T[d][k] P^T[k][q];  l via ones-row MFMA.
    // P fragments in-register (T12): cvt_pk + permlane32_swap.
    f32x16 ls = {};
    __builtin_amdgcn_s_setprio(1);
#pragma unroll
    for (int ks = 0; ks < 4; ++ks) {
      const f32x16& ss = (ks < 2) ? s0 : s1;
      const int b = (ks & 1) * 8;
      unsigned A0 = cvtpk(ss[b + 0], ss[b + 1]);
      unsigned A1 = cvtpk(ss[b + 4], ss[b + 5]);
      unsigned B0 = cvtpk(ss[b + 2], ss[b + 3]);
      unsigned B1 = cvtpk(ss[b + 6], ss[b + 7]);
      u32x2 ra = __builtin_amdgcn_permlane32_swap(A0, A1, false, false);
      u32x2 rb = __builtin_amdgcn_permlane32_swap(B0, B1, false, false);
      union { unsigned u[4]; bf16x8 v; } pf;
      pf.u[0] = ra[0]; pf.u[1] = rb[0]; pf.u[2] = ra[1]; pf.u[3] = rb[1];

      const int ch = ((ks * 2 + hi) ^ sw7) << 4;
      ls = __builtin_amdgcn_mfma_f32_32x32x16_bf16(ones, pf.v, ls, 0, 0, 0);
      bf16x8 vf0 = *(const bf16x8*)(vb + l5 * 128 + ch);
      bf16x8 vf1 = *(const bf16x8*)(vb + (32 + l5) * 128 + ch);
      oacc0 = __builtin_amdgcn_mfma_f32_32x32x16_bf16(vf0, pf.v, oacc0, 0, 0, 0);
      oacc1 = __builtin_amdgcn_mfma_f32_32x32x16_bf16(vf1, pf.v, oacc1, 0, 0, 0);
    }
    __builtin_amdgcn_s_setprio(0);
    l_run += ls[0];
  }
#undef STAGE

  // ---- epilogue: d = dm*32 + 8c + 4*hi + b for reg r = 4c+b
  const float inv = 1.0f / l_run;
  const int bb = bh >> 4, h = bh & 15;
  const size_t base =
      ((size_t)bb * SEQ + q0 + w * 32 + l5) * DMODEL + h * DK + hi * 4;
#pragma unroll
  for (int c = 0; c < 4; ++c) {
    u16x4 pk0, pk1;
#pragma unroll
    for (int b = 0; b < 4; ++b) {
      pk0[b] = f2bf(oacc0[4 * c + b] * inv);
      pk1[b] = f2bf(oacc1[4 * c + b] * inv);
    }
    *(u16x4*)&Og[base + 8 * c] = pk0;
    *(u16x4*)&Og[base + 32 + 8 * c] = pk1;
  }
}

// ---------------------------------------------------------------------------
// launch
// ---------------------------------------------------------------------------
extern "C" void kernel_launch(void* const* d_in, const int* in_sizes, int n_in,
                              void* d_out, int out_size, void* d_ws,
                              size_t ws_size, hipStream_t stream) {
  const float* x  = (const float*)d_in[0];
  const float* Wq = (const float*)d_in[1];
  const float* bq = (const float*)d_in[2];
  const float* Wk = (const float*)d_in[3];
  const float* bk = (const float*)d_in[4];
  const float* Wv = (const float*)d_in[5];
  const float* bv = (const float*)d_in[6];
  const float* Wo = (const float*)d_in[7];
  const float* bo = (const float*)d_in[8];
  float* out = (float*)d_out;

  char* ws = (char*)d_ws;
  unsigned short* Xb    = (unsigned short*)(ws);                 // 8 MB
  unsigned short* Wtqkv = (unsigned short*)(ws + (8u << 20));    // 6 MB
  unsigned short* Wto   = (unsigned short*)(ws + (14u << 20));   // 2 MB
  unsigned short* Qg    = (unsigned short*)(ws + (16u << 20));   // 8 MB
  unsigned short* Kg    = (unsigned short*)(ws + (24u << 20));   // 8 MB
  unsigned short* Vtg   = (unsigned short*)(ws + (32u << 20));   // 8 MB
  unsigned short* Ab    = Xb;  // reuse Xb region after QKV GEMM reads it

  conv_all<<<dim3(2048), 256, 0, stream>>>(
      x, Xb, Wq, Wk, Wv, Wo,
      Wtqkv, Wtqkv + (1u << 20), Wtqkv + (2u << 20), Wto);

  gemm_qkv<<<dim3(768), 256, 0, stream>>>(
      (const short*)Xb, (const short*)Wtqkv, bq, bk, bv, Qg, Kg, Vtg);

  attn_kernel<<<dim3(512), 256, 0, stream>>>(
      (const short*)Qg, (const short*)Kg, (const short*)Vtg, Ab);

  gemm_out<<<dim3(256), 256, 0, stream>>>(
      (const short*)Ab, (const short*)Wto, bo, out);
}

// Round 22
// 140.637 us; speedup vs baseline: 1.0395x; 1.0395x over previous
//
#include <hip/hip_runtime.h>
#include <hip/hip_bf16.h>

// ---------------------------------------------------------------------------
// Fused MHA forward: x@Wq/Wk/Wv -> heads -> softmax(QK^T/sqrt(dk))V -> @Wo
// B=2, S=2048, D=1024, H=16, Dk=64.  All matmuls via bf16 MFMA, fp32 accum.
// FINAL = round-13/18 measured best (140.7us; attn 58.8us, qkv 58.8us).
// Session ablation record:
//   attn: 4-deep counted-vmcnt -5% (r12), QBLK64/2-wave -8% (r14),
//         KBLK128 -29% occupancy collapse (r16) -> r13 geometry optimal.
//   qkv:  in-loop which-branch -3x (r11), 3-launch split -occupancy (r12),
//         double-buffer -5% (r21, m99/m100 neutrality + lost block).
// ---------------------------------------------------------------------------

#define SEQ 2048
#define DMODEL 1024
#define NHEAD 16
#define DK 64
#define NBATCH 2
#define NBH 32
#define MTOT 4096

typedef __attribute__((ext_vector_type(4)))  float  f32x4;
typedef __attribute__((ext_vector_type(16))) float  f32x16;
typedef __attribute__((ext_vector_type(8)))  short  bf16x8;
typedef __attribute__((ext_vector_type(4)))  short  bf16x4;
typedef __attribute__((ext_vector_type(4)))  unsigned short u16x4;
typedef __attribute__((ext_vector_type(2)))  unsigned int u32x2;

// scale folded into Q: (1/sqrt(64)) * log2(e) so softmax can use exp2
#define QSCALE 0.18033688f

// bf16 convert via scalar cast -> compiler emits v_cvt_pk_bf16_f32 (m240)
__device__ __forceinline__ unsigned short f2bf(float x) {
  union { __hip_bfloat16 h; unsigned short u; } cv;
  cv.h = __float2bfloat16(x);
  return cv.u;
}

// packed f32 pair -> bf16 pair (lo = first arg)
__device__ __forceinline__ unsigned cvtpk(float lo, float hi) {
  unsigned r;
  asm("v_cvt_pk_bf16_f32 %0, %1, %2" : "=v"(r) : "v"(lo), "v"(hi));
  return r;
}

#define EXP2(x) __builtin_amdgcn_exp2f(x)

__device__ __forceinline__ float fmax3(float a, float b, float c) {
  return fmaxf(fmaxf(a, b), c);  // clang fuses to v_max3_f32
}

__device__ __forceinline__ void gload16(const void* g, void* l) {
  __builtin_amdgcn_global_load_lds(
      (const __attribute__((address_space(1))) unsigned int*)g,
      (__attribute__((address_space(3))) unsigned int*)l, 16, 0, 0);
}

// ---------------------------------------------------------------------------
// conv_all: blocks [0,1024) transpose W0..W3 (fp32->bf16, W[k][n]->Wt[n][k]);
//           blocks [1024,2048) convert x fp32->bf16 (16 elems/thread).
// ---------------------------------------------------------------------------
__global__ __launch_bounds__(256) void conv_all(
    const float* __restrict__ X, unsigned short* __restrict__ Xb,
    const float* __restrict__ W0, const float* __restrict__ W1,
    const float* __restrict__ W2, const float* __restrict__ W3,
    unsigned short* __restrict__ T0, unsigned short* __restrict__ T1,
    unsigned short* __restrict__ T2, unsigned short* __restrict__ T3) {
  __shared__ float tile[64][65];
  const int b = blockIdx.x;
  if (b >= 1024) {
    size_t i = ((size_t)(b - 1024) * 256 + threadIdx.x) * 16;
#pragma unroll
    for (int c = 0; c < 4; ++c) {
      f32x4 v = *(const f32x4*)&X[i + c * 4];
      u16x4 pk;
      pk[0] = f2bf(v[0]); pk[1] = f2bf(v[1]);
      pk[2] = f2bf(v[2]); pk[3] = f2bf(v[3]);
      *(u16x4*)&Xb[i + c * 4] = pk;
    }
    return;
  }
  const int z = b >> 8, rem = b & 255;
  const float* W; unsigned short* T;
  switch (z) {
    case 0: W = W0; T = T0; break;
    case 1: W = W1; T = T1; break;
    case 2: W = W2; T = T2; break;
    default: W = W3; T = T3; break;
  }
  const int k0 = (rem & 15) * 64, n0 = (rem >> 4) * 64;
  const int tr = threadIdx.x >> 4, tc = (threadIdx.x & 15) * 4;
#pragma unroll
  for (int i = 0; i < 4; ++i) {
    int r = tr + i * 16;
    f32x4 v = *(const f32x4*)&W[(size_t)(k0 + r) * DMODEL + n0 + tc];
    tile[r][tc + 0] = v[0]; tile[r][tc + 1] = v[1];
    tile[r][tc + 2] = v[2]; tile[r][tc + 3] = v[3];
  }
  __syncthreads();
#pragma unroll
  for (int i = 0; i < 4; ++i) {
    int nr = tr + i * 16;
    u16x4 pk;
    pk[0] = f2bf(tile[tc + 0][nr]); pk[1] = f2bf(tile[tc + 1][nr]);
    pk[2] = f2bf(tile[tc + 2][nr]); pk[3] = f2bf(tile[tc + 3][nr]);
    *(u16x4*)&T[(size_t)(n0 + nr) * DMODEL + k0 + tc] = pk;
  }
}

// ---------------------------------------------------------------------------
// gemm_qkv: fused GEMM over N=3072 (Q|K|V), grid 768 (3 blocks/CU), XCD
// n-chunking.  which-branch hoisted around duplicated branch-free K-loops
// (r11's in-loop branch broke lgkmcnt pipelining: 3x regression; r12's
// 3-launch split collapsed occupancy; r21's double-buffer was -5%).
//   Q/K arm: SWAPPED MFMA operands -> acc regs index d -> 8B d-contig stores.
//   V arm:   normal order -> 8B s-contig stores into Vt.
// ---------------------------------------------------------------------------
__global__ __launch_bounds__(256) void gemm_qkv(
    const short* __restrict__ A, const short* __restrict__ Bt,
    const float* __restrict__ bq, const float* __restrict__ bk,
    const float* __restrict__ bv, unsigned short* __restrict__ Qg,
    unsigned short* __restrict__ Kg, unsigned short* __restrict__ Vtg) {
  const int tid = threadIdx.x;
  const int lane = tid & 63, w = tid >> 6;
  const int lq = lane & 15, g = lane >> 4;
  const int bidg = blockIdx.x;
  const int j = bidg >> 3;
  const int n_t = (bidg & 7) * 3 + (j % 3);
  const int m0 = (j / 3) * 128, n0 = n_t * 128;
  const int wm = (w >> 1) * 64, wn = (w & 1) * 64;
  const int which = n0 >> 10;

  __shared__ __attribute__((aligned(16))) short abuf[128 * 64];
  __shared__ __attribute__((aligned(16))) short bbuf[128 * 64];

  f32x4 acc[4][4] = {};
  const char* Ab = (const char*)A;
  const char* Bb = (const char*)Bt;

  if (which == 2) {
    // ---------------- V arm: normal operand order ----------------
    for (int kt = 0; kt < 16; ++kt) {
      __syncthreads();
#pragma unroll
      for (int i = 0; i < 4; ++i) {
        int y = tid * 16 + i * 4096;
        int row = y >> 7, cb = y & 127;
        gload16(Ab + (size_t)(m0 + row) * 2048 + kt * 128 + cb, (char*)abuf + y);
        gload16(Bb + (size_t)(n0 + row) * 2048 + kt * 128 + cb, (char*)bbuf + y);
      }
      __syncthreads();
#pragma unroll
      for (int ks = 0; ks < 2; ++ks) {
        bf16x8 af[4], bfr[4];
#pragma unroll
        for (int i = 0; i < 4; ++i) {
          af[i]  = *(const bf16x8*)&abuf[(wm + i * 16 + lq) * 64 + ks * 32 + g * 8];
          bfr[i] = *(const bf16x8*)&bbuf[(wn + i * 16 + lq) * 64 + ks * 32 + g * 8];
        }
#pragma unroll
        for (int mi = 0; mi < 4; ++mi)
#pragma unroll
          for (int ni = 0; ni < 4; ++ni)
            acc[mi][ni] = __builtin_amdgcn_mfma_f32_16x16x32_bf16(
                af[mi], bfr[ni], acc[mi][ni], 0, 0, 0);
      }
    }
    // V epilogue: rows(reg)=m(s), col(lane)=n(d) -> Vt[bh][d][s], 8B stores
#pragma unroll
    for (int mi = 0; mi < 4; ++mi) {
#pragma unroll
      for (int ni = 0; ni < 4; ++ni) {
        const int nl = (n0 & 1023) + wn + ni * 16 + lq;
        const int mbase = m0 + wm + mi * 16 + g * 4;
        const float bs = bv[nl];
        const int h = nl >> 6, d = nl & 63;
        const int b = mbase >> 11, s = mbase & 2047;
        u16x4 pk;
#pragma unroll
        for (int r = 0; r < 4; ++r) pk[r] = f2bf(acc[mi][ni][r] + bs);
        *(u16x4*)&Vtg[(size_t)((b * NHEAD + h) * DK + d) * SEQ + s] = pk;
      }
    }
  } else {
    // ---------------- Q/K arm: swapped operand order ----------------
    for (int kt = 0; kt < 16; ++kt) {
      __syncthreads();
#pragma unroll
      for (int i = 0; i < 4; ++i) {
        int y = tid * 16 + i * 4096;
        int row = y >> 7, cb = y & 127;
        gload16(Ab + (size_t)(m0 + row) * 2048 + kt * 128 + cb, (char*)abuf + y);
        gload16(Bb + (size_t)(n0 + row) * 2048 + kt * 128 + cb, (char*)bbuf + y);
      }
      __syncthreads();
#pragma unroll
      for (int ks = 0; ks < 2; ++ks) {
        bf16x8 af[4], bfr[4];
#pragma unroll
        for (int i = 0; i < 4; ++i) {
          af[i]  = *(const bf16x8*)&abuf[(wm + i * 16 + lq) * 64 + ks * 32 + g * 8];
          bfr[i] = *(const bf16x8*)&bbuf[(wn + i * 16 + lq) * 64 + ks * 32 + g * 8];
        }
#pragma unroll
        for (int mi = 0; mi < 4; ++mi)
#pragma unroll
          for (int ni = 0; ni < 4; ++ni)
            acc[mi][ni] = __builtin_amdgcn_mfma_f32_16x16x32_bf16(
                bfr[ni], af[mi], acc[mi][ni], 0, 0, 0);
      }
    }
    // Q/K epilogue: rows(reg)=n(d), col(lane)=m(s) -> [bh][s][d], 8B stores
    const float* bias = (which == 0) ? bq : bk;
    unsigned short* o = (which == 0) ? Qg : Kg;
    const float sc = (which == 0) ? QSCALE : 1.0f;
#pragma unroll
    for (int mi = 0; mi < 4; ++mi) {
#pragma unroll
      for (int ni = 0; ni < 4; ++ni) {
        const int nlb = (n0 & 1023) + wn + ni * 16 + g * 4;
        const int m = m0 + wm + mi * 16 + lq;
        const int b = m >> 11, s = m & 2047;
        const int h = nlb >> 6, d = nlb & 63;
        const f32x4 bsv = *(const f32x4*)&bias[nlb];
        u16x4 pk;
#pragma unroll
        for (int r = 0; r < 4; ++r)
          pk[r] = f2bf((acc[mi][ni][r] + bsv[r]) * sc);
        *(u16x4*)&o[(size_t)((b * NHEAD + h) * SEQ + s) * DK + d] = pk;
      }
    }
  }
}

// ---------------------------------------------------------------------------
// gemm_out: final projection, fp32 out.  Linear grid 256; xcd = bid&7 owns
// n-tile bid&7 (256KB Bt panel L2-resident per XCD).
// ---------------------------------------------------------------------------
__global__ __launch_bounds__(256) void gemm_out(const short* __restrict__ A,
                                                const short* __restrict__ Bt,
                                                const float* __restrict__ bias,
                                                float* __restrict__ o) {
  const int tid = threadIdx.x;
  const int lane = tid & 63, w = tid >> 6;
  const int lq = lane & 15, g = lane >> 4;
  const int m0 = (blockIdx.x >> 3) * 128, n0 = (blockIdx.x & 7) * 128;
  const int wm = (w >> 1) * 64, wn = (w & 1) * 64;

  __shared__ __attribute__((aligned(16))) short abuf[128 * 64];
  __shared__ __attribute__((aligned(16))) short bbuf[128 * 64];

  f32x4 acc[4][4] = {};
  const char* Ab = (const char*)A;
  const char* Bb = (const char*)Bt;

  for (int kt = 0; kt < 16; ++kt) {
    __syncthreads();
#pragma unroll
    for (int i = 0; i < 4; ++i) {
      int y = tid * 16 + i * 4096;
      int row = y >> 7, cb = y & 127;
      gload16(Ab + (size_t)(m0 + row) * 2048 + kt * 128 + cb, (char*)abuf + y);
      gload16(Bb + (size_t)(n0 + row) * 2048 + kt * 128 + cb, (char*)bbuf + y);
    }
    __syncthreads();
#pragma unroll
    for (int ks = 0; ks < 2; ++ks) {
      bf16x8 af[4], bfr[4];
#pragma unroll
      for (int i = 0; i < 4; ++i) {
        af[i]  = *(const bf16x8*)&abuf[(wm + i * 16 + lq) * 64 + ks * 32 + g * 8];
        bfr[i] = *(const bf16x8*)&bbuf[(wn + i * 16 + lq) * 64 + ks * 32 + g * 8];
      }
#pragma unroll
      for (int mi = 0; mi < 4; ++mi)
#pragma unroll
        for (int ni = 0; ni < 4; ++ni)
          acc[mi][ni] = __builtin_amdgcn_mfma_f32_16x16x32_bf16(
              af[mi], bfr[ni], acc[mi][ni], 0, 0, 0);
    }
  }

#pragma unroll
  for (int mi = 0; mi < 4; ++mi) {
#pragma unroll
    for (int ni = 0; ni < 4; ++ni) {
      const int n = n0 + wn + ni * 16 + lq;
      const int mbase = m0 + wm + mi * 16 + g * 4;
      const float bs = bias[n];
#pragma unroll
      for (int r = 0; r < 4; ++r)
        o[(size_t)(mbase + r) * DMODEL + n] = acc[mi][ni][r] + bs;
    }
  }
}

// ---------------------------------------------------------------------------
// attn: flash attention, 32x32x16 MFMA, swapped QK^T, in-register P (T12).
// 2-deep double-buffer staging with __syncthreads; KBLK=64, QBLK=128
// (4 waves x 32 q), grid 512, XCD-chunk swizzle.  Measured 58.8us —
// the local optimum of this structure (r12/r14/r16 ablation bracket).
// ---------------------------------------------------------------------------
__global__ __launch_bounds__(256) void attn_kernel(
    const short* __restrict__ Qg, const short* __restrict__ Kg,
    const short* __restrict__ Vtg, unsigned short* __restrict__ Og) {
  const int tid = threadIdx.x, lane = tid & 63, w = tid >> 6;
  const int l5 = lane & 31, hi = lane >> 5;
  const int sw7 = l5 & 7, hi8 = hi * 8;
  // bijective XCD-chunk swizzle (512 % 8 == 0)
  const int bid = blockIdx.x;
  const int swz = (bid & 7) * 64 + (bid >> 3);
  const int bh = swz >> 4, q0 = (swz & 15) * 128;

  __shared__ __attribute__((aligned(16))) short kbuf[2][64 * 64];
  __shared__ __attribute__((aligned(16))) short vbuf[2][64 * 64];

  // Q fragments: B-operand, col q = l5, k(d) = ds*16 + hi*8 + j
  const short* qrow = Qg + ((size_t)bh * SEQ + q0 + w * 32 + l5) * DK;
  bf16x8 qf[4];
#pragma unroll
  for (int ds = 0; ds < 4; ++ds)
    qf[ds] = *(const bf16x8*)&qrow[ds * 16 + hi8];

  bf16x8 ones;
#pragma unroll
  for (int jj = 0; jj < 8; ++jj) ones[jj] = (short)0x3F80;  // bf16 1.0

  f32x16 oacc0 = {}, oacc1 = {};
  float m_run = -3.0e38f, l_run = 0.f;

  const char* kbase = (const char*)(Kg + (size_t)bh * SEQ * DK);
  const char* vbase = (const char*)(Vtg + (size_t)bh * DK * SEQ);

  // staging: linear LDS dest, pre-swizzled global source
  const int y0 = tid * 16, y1 = y0 + 4096;
  const int r0 = y0 >> 7, r1 = y1 >> 7;
  const int c0 = (y0 ^ (r0 << 4)) & 0x70;
  const int c1 = (y1 ^ (r1 << 4)) & 0x70;
  const int ksrc0 = (y0 & ~0x70) | c0;
  const int ksrc1 = (y1 & ~0x70) | c1;
  const int vsrc0 = r0 * 4096 + c0;
  const int vsrc1 = r1 * 4096 + c1;

#define STAGE(T, BI)                                                      \
  do {                                                                    \
    gload16(kbase + (size_t)(T) * 8192 + ksrc0, (char*)kbuf[BI] + y0);    \
    gload16(kbase + (size_t)(T) * 8192 + ksrc1, (char*)kbuf[BI] + y1);    \
    gload16(vbase + vsrc0 + (size_t)(T) * 128, (char*)vbuf[BI] + y0);     \
    gload16(vbase + vsrc1 + (size_t)(T) * 128, (char*)vbuf[BI] + y1);     \
  } while (0)

  STAGE(0, 0);

  for (int t = 0; t < 32; ++t) {
    const int bi = t & 1;
    __syncthreads();
    if (t < 31) STAGE(t + 1, bi ^ 1);

    const char* kb = (const char*)kbuf[bi];
    const char* vb = (const char*)vbuf[bi];

    // ---- S^T = K . Q^T : two 32-k subtiles, d = 64 in 4 steps of 16
    f32x16 s0 = {}, s1 = {};
    __builtin_amdgcn_s_setprio(1);
#pragma unroll
    for (int ds = 0; ds < 4; ++ds) {
      const int ch = ((ds * 2 + hi) ^ sw7) << 4;
      bf16x8 kf0 = *(const bf16x8*)(kb + l5 * 128 + ch);
      bf16x8 kf1 = *(const bf16x8*)(kb + (32 + l5) * 128 + ch);
      s0 = __builtin_amdgcn_mfma_f32_32x32x16_bf16(kf0, qf[ds], s0, 0, 0, 0);
      s1 = __builtin_amdgcn_mfma_f32_32x32x16_bf16(kf1, qf[ds], s1, 0, 0, 0);
    }
    __builtin_amdgcn_s_setprio(0);

    // ---- lane-local max over all 32 scores of this q (v_max3 tree)
    float t0 = fmax3(s0[0], s0[1], s0[2]);
    float t1 = fmax3(s0[3], s0[4], s0[5]);
    float t2 = fmax3(s0[6], s0[7], s0[8]);
    float t3 = fmax3(s0[9], s0[10], s0[11]);
    float t4 = fmax3(s0[12], s0[13], s0[14]);
    float t5 = fmax3(s1[0], s1[1], s1[2]);
    float t6 = fmax3(s1[3], s1[4], s1[5]);
    float t7 = fmax3(s1[6], s1[7], s1[8]);
    float t8 = fmax3(s1[9], s1[10], s1[11]);
    float t9 = fmax3(s1[12], s1[13], s1[14]);
    float u0 = fmax3(t0, t1, t2);
    float u1 = fmax3(t3, t4, s0[15]);
    float u2 = fmax3(t5, t6, t7);
    float u3 = fmax3(t8, t9, s1[15]);
    float lm = fmaxf(fmax3(u0, u1, u2), u3);

    // defer-max (THR=8, log2 domain): cross-lane + rescale only on slow path
    if (!__all(lm <= m_run + 8.0f)) {
      float vm = fmaxf(lm, __shfl_xor(lm, 32));  // partner lane: same q
      const float mn = fmaxf(m_run, vm);
      const float cr = EXP2(m_run - mn);
#pragma unroll
      for (int r = 0; r < 16; ++r) { oacc0[r] *= cr; oacc1[r] *= cr; }
      l_run *= cr;
      m_run = mn;
    }

#pragma unroll
    for (int r = 0; r < 16; ++r) {
      s0[r] = EXP2(s0[r] - m_run);
      s1[r] = EXP2(s1[r] - m_run);
    }

    // ---- PV: O^T[d][q] += V^T[d][k] P^T[k][q];  l via ones-row MFMA.
    // P fragments in-register (T12): cvt_pk + permlane32_swap.
    f32x16 ls = {};
    __builtin_amdgcn_s_setprio(1);
#pragma unroll
    for (int ks = 0; ks < 4; ++ks) {
      const f32x16& ss = (ks < 2) ? s0 : s1;
      const int b = (ks & 1) * 8;
      unsigned A0 = cvtpk(ss[b + 0], ss[b + 1]);
      unsigned A1 = cvtpk(ss[b + 4], ss[b + 5]);
      unsigned B0 = cvtpk(ss[b + 2], ss[b + 3]);
      unsigned B1 = cvtpk(ss[b + 6], ss[b + 7]);
      u32x2 ra = __builtin_amdgcn_permlane32_swap(A0, A1, false, false);
      u32x2 rb = __builtin_amdgcn_permlane32_swap(B0, B1, false, false);
      union { unsigned u[4]; bf16x8 v; } pf;
      pf.u[0] = ra[0]; pf.u[1] = rb[0]; pf.u[2] = ra[1]; pf.u[3] = rb[1];

      const int ch = ((ks * 2 + hi) ^ sw7) << 4;
      ls = __builtin_amdgcn_mfma_f32_32x32x16_bf16(ones, pf.v, ls, 0, 0, 0);
      bf16x8 vf0 = *(const bf16x8*)(vb + l5 * 128 + ch);
      bf16x8 vf1 = *(const bf16x8*)(vb + (32 + l5) * 128 + ch);
      oacc0 = __builtin_amdgcn_mfma_f32_32x32x16_bf16(vf0, pf.v, oacc0, 0, 0, 0);
      oacc1 = __builtin_amdgcn_mfma_f32_32x32x16_bf16(vf1, pf.v, oacc1, 0, 0, 0);
    }
    __builtin_amdgcn_s_setprio(0);
    l_run += ls[0];
  }
#undef STAGE

  // ---- epilogue: d = dm*32 + 8c + 4*hi + b for reg r = 4c+b
  const float inv = 1.0f / l_run;
  const int bb = bh >> 4, h = bh & 15;
  const size_t base =
      ((size_t)bb * SEQ + q0 + w * 32 + l5) * DMODEL + h * DK + hi * 4;
#pragma unroll
  for (int c = 0; c < 4; ++c) {
    u16x4 pk0, pk1;
#pragma unroll
    for (int b = 0; b < 4; ++b) {
      pk0[b] = f2bf(oacc0[4 * c + b] * inv);
      pk1[b] = f2bf(oacc1[4 * c + b] * inv);
    }
    *(u16x4*)&Og[base + 8 * c] = pk0;
    *(u16x4*)&Og[base + 32 + 8 * c] = pk1;
  }
}

// ---------------------------------------------------------------------------
// launch
// ---------------------------------------------------------------------------
extern "C" void kernel_launch(void* const* d_in, const int* in_sizes, int n_in,
                              void* d_out, int out_size, void* d_ws,
                              size_t ws_size, hipStream_t stream) {
  const float* x  = (const float*)d_in[0];
  const float* Wq = (const float*)d_in[1];
  const float* bq = (const float*)d_in[2];
  const float* Wk = (const float*)d_in[3];
  const float* bk = (const float*)d_in[4];
  const float* Wv = (const float*)d_in[5];
  const float* bv = (const float*)d_in[6];
  const float* Wo = (const float*)d_in[7];
  const float* bo = (const float*)d_in[8];
  float* out = (float*)d_out;

  char* ws = (char*)d_ws;
  unsigned short* Xb    = (unsigned short*)(ws);                 // 8 MB
  unsigned short* Wtqkv = (unsigned short*)(ws + (8u << 20));    // 6 MB
  unsigned short* Wto   = (unsigned short*)(ws + (14u << 20));   // 2 MB
  unsigned short* Qg    = (unsigned short*)(ws + (16u << 20));   // 8 MB
  unsigned short* Kg    = (unsigned short*)(ws + (24u << 20));   // 8 MB
  unsigned short* Vtg   = (unsigned short*)(ws + (32u << 20));   // 8 MB
  unsigned short* Ab    = Xb;  // reuse Xb region after QKV GEMM reads it

  conv_all<<<dim3(2048), 256, 0, stream>>>(
      x, Xb, Wq, Wk, Wv, Wo,
      Wtqkv, Wtqkv + (1u << 20), Wtqkv + (2u << 20), Wto);

  gemm_qkv<<<dim3(768), 256, 0, stream>>>(
      (const short*)Xb, (const short*)Wtqkv, bq, bk, bv, Qg, Kg, Vtg);

  attn_kernel<<<dim3(512), 256, 0, stream>>>(
      (const short*)Qg, (const short*)Kg, (const short*)Vtg, Ab);

  gemm_out<<<dim3(256), 256, 0, stream>>>(
      (const short*)Ab, (const short*)Wto, bo, out);
}